// Round 3
// baseline (112.343 us; speedup 1.0000x reference)
//
#include <hip/hip_runtime.h>
#include <hip/hip_bf16.h>
#include <hip/hip_fp8.h>

// SimCLR NT-Xent loss on MI355X.
// loss = -(1/2B) sum_t [ 10*G[t,j0(t)] - (10 + log sum_{j!=t} exp(10*G[t,j]-10)) ]
// where G = M M^T, M = l2norm rows of [z_i; z_j], j0 = (t%B==0) ? 1 : 0.
// Round 8: MX-scaled fp8 MFMA (mfma_scale_f32_32x32x64_f8f6f4, unity e8m0
// scales = 0x7F -> 2^0). 2x matrix rate vs 16x16x32 fp8 (4686 vs 2190 TF
// ubench; m145->m148 ladder 995->1628 TF on this same 128^2 structure).
// One MFMA consumes the whole K=64 chunk per 32x32 acc block. Staging +
// swizzle from round 7 reused unchanged: each 16B granule is its own
// ds_read_b128 at its swizzled slot (halves to separate VGPR quads, so
// granule-pair swap under odd XOR is harmless); 64 lanes cover all 32
// banks at the 8-cycle wave minimum. Keeps KB=64 dbuf, 1 barrier/chunk,
// 4 blocks/CU.

#define BB 4096      // batch B
#define DD 512       // feature dim (bytes per row in fp8)
#define NN 8192      // 2B rows of G
#define TILE 128     // block tile (rows x cols)
#define KB 64        // K bytes (=elements) staged per LDS chunk
#define NBLK 2080    // 64*65/2 upper-triangle block tiles

typedef __attribute__((ext_vector_type(4)))  float f32x4;
typedef __attribute__((ext_vector_type(16))) float f32x16;
typedef __attribute__((ext_vector_type(4)))  int   i32x4;
typedef __attribute__((ext_vector_type(8)))  int   i32x8;

#define AS1 __attribute__((address_space(1)))
#define AS3 __attribute__((address_space(3)))
static __device__ __forceinline__ void gload_lds16(const void* g, void* l) {
    __builtin_amdgcn_global_load_lds((const AS1 void*)g, (AS3 void*)l, 16, 0, 0);
}

// ---------------- kernel 1: L2-normalize rows, cast to fp8; zero rowsum ----
// One wave per row: 64 lanes x 8 f32, shuffle reduce, no LDS/barrier.
__global__ __launch_bounds__(256)
void normalize_kernel(const float* __restrict__ zi, const float* __restrict__ zj,
                      unsigned char* __restrict__ M, float* __restrict__ rowsum) {
    const int wave = threadIdx.x >> 6;
    const int lane = threadIdx.x & 63;
    const int row  = blockIdx.x * 4 + wave;      // 2048 blocks * 4 rows
    if (threadIdx.x < 4) rowsum[blockIdx.x * 4 + threadIdx.x] = 0.f;
    const float* src = (row < BB) ? (zi + (size_t)row * DD)
                                  : (zj + (size_t)(row - BB) * DD);
    float4 v0 = ((const float4*)src)[lane * 2 + 0];
    float4 v1 = ((const float4*)src)[lane * 2 + 1];
    float ss = v0.x*v0.x + v0.y*v0.y + v0.z*v0.z + v0.w*v0.w
             + v1.x*v1.x + v1.y*v1.y + v1.z*v1.z + v1.w*v1.w;
    #pragma unroll
    for (int off = 1; off <= 32; off <<= 1) ss += __shfl_xor(ss, off);
    const float inv = rsqrtf(ss);
    const float vals[8] = {v0.x*inv, v0.y*inv, v0.z*inv, v0.w*inv,
                           v1.x*inv, v1.y*inv, v1.z*inv, v1.w*inv};
    union { long u; unsigned char b[8]; } pk;
    #pragma unroll
    for (int j = 0; j < 8; ++j)
        pk.b[j] = __hip_cvt_float_to_fp8(vals[j], __HIP_SATFINITE, __HIP_E4M3);
    ((long*)(M + (size_t)row * DD))[lane] = pk.u;
}

// ---------------- kernel 2: Gram tile + exp row/col sums -------------------
// 2080 blocks, one upper-triangle 128x128 tile each (by >= bx).
// Wave w: 64x64 output region at wr=(w>>1)*64, wc=(w&1)*64; 2x2 of 32x32.
// LDS: double-buffered; each buffer row-major 128 rows x 64 B, XOR-swizzled
// 16B granules: row r stores source granule sg at position sg ^ ((r>>1)&3).
// Gather side inverts the swizzle so global_load_lds's lane-linear dest
// constraint is satisfied (source addr carries the permutation).
__global__ __launch_bounds__(256, 4)
void gram_lse_kernel(const unsigned char* __restrict__ Mg,
                     float* __restrict__ rowsum, float* __restrict__ targets) {
    __shared__ __align__(16) char As[2][TILE * KB];   // 2 x 8 KB
    __shared__ __align__(16) char Bs[2][TILE * KB];   // 2 x 8 KB

    // XCD-banded order: dispatch d -> band d%8 (one XCD), 260 tiles per band.
    const int d = blockIdx.x;
    const int p = (d & 7) * 260 + (d >> 3);
    // triangular decode: p -> (bx, by) with by >= bx
    int by = (int)((sqrtf(8.0f * (float)p + 1.0f) - 1.0f) * 0.5f);
    while ((by + 1) * (by + 2) / 2 <= p) ++by;
    while (by * (by + 1) / 2 > p) --by;
    const int bx = p - by * (by + 1) / 2;

    const int rowBase = bx * TILE;
    const int colBase = by * TILE;
    const bool diag = (bx == by);
    const int tid  = threadIdx.x;
    const int wave = tid >> 6;
    const int lane = tid & 63;
    const int wr = (wave >> 1) * 64;
    const int wc = (wave & 1) * 64;
    const int l31 = lane & 31;
    const int h0  = lane >> 5;          // k-half: lanes 0-31 k[0:32), 32-63 k[32:64)

    // staging gather pattern (constant per thread across issues & chunks):
    //   dest granule q = issue*256 + tid -> row = issue*64 + (tid>>2),
    //   stored pos s = tid&3, source granule sg = s ^ ((row>>1)&3)
    //   = (tid&3) ^ ((tid>>3)&3)  (issue*64 drops out mod 4).
    const int sg  = (tid & 3) ^ ((tid >> 3) & 3);   // source granule within row
    const int sr0 = tid >> 2;                        // source row base (+64/issue)
    const unsigned char* gA0 = Mg + (size_t)(rowBase + sr0) * DD + sg * 16;
    const unsigned char* gB0 = Mg + (size_t)(colBase + sr0) * DD + sg * 16;

    // fragment read: lane needs row = wr/wc + mi*32 + l31, k-bytes
    // [h0*32, h0*32+32) = granules {2h0, 2h0+1}, stored at positions
    // (2h0)^sw and ((2h0)^sw)^1, sw = ((l31)>>1)&3 (wr/wc/mi*32 drop out).
    // Each granule is one independent ds_read_b128 -> order explicit.
    const int sw  = (l31 >> 1) & 3;
    const int plo = (2 * h0) ^ sw;
    const int phi = plo ^ 1;
    const int aoffL = (wr + l31) * KB + plo * 16;
    const int aoffH = (wr + l31) * KB + phi * 16;
    const int boffL = (wc + l31) * KB + plo * 16;
    const int boffH = (wc + l31) * KB + phi * 16;

    f32x16 acc[2][2] = {};

    // ---- prologue: stage chunk 0 into buffer 0 ----
    {
        char* lA = As[0] + tid * 16;
        #pragma unroll
        for (int i = 0; i < 2; ++i)
            gload_lds16(gA0 + (size_t)i * 64 * DD, lA + i * 4096);
        if (!diag) {
            char* lB = Bs[0] + tid * 16;
            #pragma unroll
            for (int i = 0; i < 2; ++i)
                gload_lds16(gB0 + (size_t)i * 64 * DD, lB + i * 4096);
        }
    }

    // ---- main loop: one barrier per chunk; stage(t+1) overlaps compute(t) ----
    #pragma unroll
    for (int t = 0; t < DD / KB; ++t) {
        // Drains vmcnt(0): chunk t (issued one full compute phase ago) has
        // landed in buffer t&1; buffer (t+1)&1 is no longer being read.
        __syncthreads();
        if (t < DD / KB - 1) {
            const int k0 = (t + 1) * KB;
            char* lA = As[(t + 1) & 1] + tid * 16;
            #pragma unroll
            for (int i = 0; i < 2; ++i)
                gload_lds16(gA0 + k0 + (size_t)i * 64 * DD, lA + i * 4096);
            if (!diag) {
                char* lB = Bs[(t + 1) & 1] + tid * 16;
                #pragma unroll
                for (int i = 0; i < 2; ++i)
                    gload_lds16(gB0 + k0 + (size_t)i * 64 * DD, lB + i * 4096);
            }
        }
        const char* Asrc = As[t & 1];
        const char* Bsrc = diag ? Asrc : Bs[t & 1];
        i32x8 a[2], b[2];
        #pragma unroll
        for (int mi = 0; mi < 2; ++mi) {
            i32x4 lo = *(const i32x4*)(Asrc + aoffL + mi * 2048);
            i32x4 hi = *(const i32x4*)(Asrc + aoffH + mi * 2048);
            a[mi] = __builtin_shufflevector(lo, hi, 0, 1, 2, 3, 4, 5, 6, 7);
        }
        #pragma unroll
        for (int ni = 0; ni < 2; ++ni) {
            i32x4 lo = *(const i32x4*)(Bsrc + boffL + ni * 2048);
            i32x4 hi = *(const i32x4*)(Bsrc + boffH + ni * 2048);
            b[ni] = __builtin_shufflevector(lo, hi, 0, 1, 2, 3, 4, 5, 6, 7);
        }
        // Unity scales: e8m0 0x7F = 2^0; opsel 0 picks byte 0 (all bytes 0x7F).
        // cbsz=0 / blgp=0 -> A,B format fp8 e4m3.
        #pragma unroll
        for (int mi = 0; mi < 2; ++mi)
            #pragma unroll
            for (int ni = 0; ni < 2; ++ni)
                acc[mi][ni] = __builtin_amdgcn_mfma_scale_f32_32x32x64_f8f6f4(
                    a[mi], b[ni], acc[mi][ni], 0, 0,
                    0, 0x7F7F7F7F, 0, 0x7F7F7F7F);
    }

    // ---- epilogue ----
    // 32x32 C/D layout: col = lane&31, row = (reg&3) + 8*(reg>>2) + 4*(lane>>5)
    // e = exp(10*G - 10) = exp2(G*C - C), C = 10*log2(e): one fma + one v_exp.
    const float C10 = 14.42695040888963f;
    float cs[2] = {0.f, 0.f};   // column partials (off-diag tiles)
    #pragma unroll
    for (int mi = 0; mi < 2; ++mi) {
        float rs[16] = {};
        #pragma unroll
        for (int ni = 0; ni < 2; ++ni) {
            const int gcol = colBase + wc + ni * 32 + l31;
            #pragma unroll
            for (int r = 0; r < 16; ++r) {
                const int lrow = (r & 3) + 8 * (r >> 2) + 4 * h0;
                const int grow = rowBase + wr + mi * 32 + lrow;
                float e = __builtin_amdgcn_exp2f(fmaf(acc[mi][ni][r], C10, -C10));
                if (grow == gcol) e = 0.f;     // exclude diagonal exactly
                rs[r] += e;
                cs[ni] += e;
                // targets: rows 0/1 of G give 10*G[t, j0] transposed.
                // Only bx==0 blocks write; disjoint col ranges -> plain store.
                if (rowBase == 0 && grow < 2) {
                    const int j0 = ((gcol & (BB - 1)) == 0) ? 1 : 0;
                    if (grow == j0) targets[gcol] = 10.f * acc[mi][ni][r];
                }
            }
        }
        // row-reduce across the 32 cols held by lanes (within each 32-half)
        #pragma unroll
        for (int m = 1; m <= 16; m <<= 1)
            #pragma unroll
            for (int r = 0; r < 16; ++r)
                rs[r] += __shfl_xor(rs[r], m);
        if (l31 == 0) {
            #pragma unroll
            for (int r = 0; r < 16; ++r)
                atomicAdd(&rowsum[rowBase + wr + mi * 32
                                  + (r & 3) + 8 * (r >> 2) + 4 * h0], rs[r]);
        }
    }
    if (!diag) {
        #pragma unroll
        for (int ni = 0; ni < 2; ++ni)
            cs[ni] += __shfl_xor(cs[ni], 32);   // combine the two k... row halves
        if (h0 == 0) {
            #pragma unroll
            for (int ni = 0; ni < 2; ++ni)
                atomicAdd(&rowsum[colBase + wc + ni * 32 + l31], cs[ni]);
        }
    }
}

// ---------------- kernel 3: final scalar reduction -------------------------
__global__ __launch_bounds__(1024)
void finalize_kernel(const float* __restrict__ rowsum,
                     const float* __restrict__ targets, float* __restrict__ out) {
    const int tid = threadIdx.x;
    float s = 0.f;
    #pragma unroll
    for (int t = tid; t < NN; t += 1024)
        s += targets[t] - 10.f - __logf(rowsum[t]);
    #pragma unroll
    for (int off = 1; off <= 32; off <<= 1) s += __shfl_xor(s, off);
    __shared__ float red[16];
    if ((tid & 63) == 0) red[tid >> 6] = s;
    __syncthreads();
    if (tid == 0) {
        float t = 0.f;
        #pragma unroll
        for (int i = 0; i < 16; ++i) t += red[i];
        out[0] = -t / (float)NN;
    }
}

extern "C" void kernel_launch(void* const* d_in, const int* in_sizes, int n_in,
                              void* d_out, int out_size, void* d_ws, size_t ws_size,
                              hipStream_t stream) {
    const float* zi = (const float*)d_in[0];
    const float* zj = (const float*)d_in[1];

    unsigned char* M = (unsigned char*)d_ws;                         // 4 MB fp8
    float* rowsum  = (float*)((char*)d_ws + (size_t)NN * DD);        // 32 KB
    float* targets = rowsum + NN;                                    // 32 KB
    float* out = (float*)d_out;

    normalize_kernel<<<NN / 4, 256, 0, stream>>>(zi, zj, M, rowsum);
    gram_lse_kernel<<<NBLK, 256, 0, stream>>>(M, rowsum, targets);
    finalize_kernel<<<1, 1024, 0, stream>>>(rowsum, targets, out);
}

// Round 4
// 108.812 us; speedup vs baseline: 1.0325x; 1.0325x over previous
//
#include <hip/hip_runtime.h>
#include <hip/hip_bf16.h>
#include <hip/hip_fp8.h>

// SimCLR NT-Xent loss on MI355X.
// loss = -(1/2B) sum_t [ 10*G[t,j0(t)] - (10 + log sum_{j!=t} exp(10*G[t,j]-10)) ]
// where G = M M^T, M = l2norm rows of [z_i; z_j], j0 = (t%B==0) ? 1 : 0.
// Round 9: ZERO-BARRIER main loop. Rounds 6-8 proved the per-chunk
// barrier+vmcnt convoy costs ~4k cy/chunk regardless of MFMA flavor
// (R3: MfmaUtil 12.5%, 85% stall). K is only 512 B/row, so: stage the
// WHOLE B panel (64 KB) to LDS once, keep each wave's 32 A rows in
// registers (64 VGPR/lane), one __syncthreads total, then 8 chunks of
// pure ds_read+MFMA with no syncs. Waves free-run and self-stagger.
// MX-scaled 32x32x64 fp8 path retained (numerics verified round 8).
// B swizzle: granule g of row r at pos g^(r&31); staging source addr
// carries the inverse (gload_lds dest stays lane-linear).

#define BB 4096      // batch B
#define DD 512       // feature dim (bytes per row in fp8)
#define NN 8192      // 2B rows of G
#define TILE 128     // block tile (rows x cols)
#define NBLK 2080    // 64*65/2 upper-triangle block tiles

typedef __attribute__((ext_vector_type(4)))  float f32x4;
typedef __attribute__((ext_vector_type(16))) float f32x16;
typedef __attribute__((ext_vector_type(4)))  int   i32x4;
typedef __attribute__((ext_vector_type(8)))  int   i32x8;

#define AS1 __attribute__((address_space(1)))
#define AS3 __attribute__((address_space(3)))
static __device__ __forceinline__ void gload_lds16(const void* g, void* l) {
    __builtin_amdgcn_global_load_lds((const AS1 void*)g, (AS3 void*)l, 16, 0, 0);
}

// ---------------- kernel 1: L2-normalize rows, cast to fp8; zero rowsum ----
// One wave per row: 64 lanes x 8 f32, shuffle reduce, no LDS/barrier.
__global__ __launch_bounds__(256)
void normalize_kernel(const float* __restrict__ zi, const float* __restrict__ zj,
                      unsigned char* __restrict__ M, float* __restrict__ rowsum) {
    const int wave = threadIdx.x >> 6;
    const int lane = threadIdx.x & 63;
    const int row  = blockIdx.x * 4 + wave;      // 2048 blocks * 4 rows
    if (threadIdx.x < 4) rowsum[blockIdx.x * 4 + threadIdx.x] = 0.f;
    const float* src = (row < BB) ? (zi + (size_t)row * DD)
                                  : (zj + (size_t)(row - BB) * DD);
    float4 v0 = ((const float4*)src)[lane * 2 + 0];
    float4 v1 = ((const float4*)src)[lane * 2 + 1];
    float ss = v0.x*v0.x + v0.y*v0.y + v0.z*v0.z + v0.w*v0.w
             + v1.x*v1.x + v1.y*v1.y + v1.z*v1.z + v1.w*v1.w;
    #pragma unroll
    for (int off = 1; off <= 32; off <<= 1) ss += __shfl_xor(ss, off);
    const float inv = rsqrtf(ss);
    const float vals[8] = {v0.x*inv, v0.y*inv, v0.z*inv, v0.w*inv,
                           v1.x*inv, v1.y*inv, v1.z*inv, v1.w*inv};
    union { long u; unsigned char b[8]; } pk;
    #pragma unroll
    for (int j = 0; j < 8; ++j)
        pk.b[j] = __hip_cvt_float_to_fp8(vals[j], __HIP_SATFINITE, __HIP_E4M3);
    ((long*)(M + (size_t)row * DD))[lane] = pk.u;
}

// ---------------- kernel 2: Gram tile + exp row/col sums -------------------
// 2080 blocks, one upper-triangle 128x128 tile each (by >= bx).
// Wave w owns output rows [w*32, w*32+32) x all 128 cols: acc[4] of 32x32.
// A: lane (l31,h0) holds row rowBase+w*32+l31, k-half h0 (8 chunks x 32B)
//    in 16 x i32x4 registers.
// B: whole col-panel in LDS, 128 rows x 512 B; granule g of row r stored
//    at pos g^(r&31) (read: 64 lanes uniform over bank groups).
__global__ __launch_bounds__(256, 2)
void gram_lse_kernel(const unsigned char* __restrict__ Mg,
                     float* __restrict__ rowsum, float* __restrict__ targets) {
    __shared__ __align__(16) char Bs[TILE * DD];   // 64 KB

    // XCD-banded order: dispatch d -> band d%8 (one XCD), 260 tiles per band.
    const int d = blockIdx.x;
    const int p = (d & 7) * 260 + (d >> 3);
    // triangular decode: p -> (bx, by) with by >= bx
    int by = (int)((sqrtf(8.0f * (float)p + 1.0f) - 1.0f) * 0.5f);
    while ((by + 1) * (by + 2) / 2 <= p) ++by;
    while (by * (by + 1) / 2 > p) --by;
    const int bx = p - by * (by + 1) / 2;

    const int rowBase = bx * TILE;
    const int colBase = by * TILE;
    const bool diag = (bx == by);
    const int tid  = threadIdx.x;
    const int wave = tid >> 6;
    const int lane = tid & 63;
    const int l31 = lane & 31;
    const int h0  = lane >> 5;          // k-half: 0 -> k[0:32), 1 -> k[32:64) per chunk

    // ---- stage whole B panel: 16 issues, 16 B per thread each ----
    // dest granule q = i*256 + tid -> row = q>>5, pos = q&31 = tid&31;
    // stored granule at pos: sg = pos ^ (row&31). Wave dest is lane-linear.
    #pragma unroll
    for (int i = 0; i < 16; ++i) {
        const int row = i * 8 + (tid >> 5);
        const int sg  = (tid & 31) ^ (row & 31);
        gload_lds16(Mg + (size_t)(colBase + row) * DD + sg * 16,
                    Bs + ((size_t)i * 256 + tid) * 16);
    }

    // ---- A rows into registers (overlaps B staging; drained at barrier) ----
    const unsigned char* Arow = Mg + (size_t)(rowBase + wave * 32 + l31) * DD + h0 * 32;
    i32x4 a4[16];
    #pragma unroll
    for (int t2 = 0; t2 < 16; ++t2)
        a4[t2] = *(const i32x4*)(Arow + (t2 >> 1) * 64 + (t2 & 1) * 16);

    __syncthreads();   // the ONLY barrier: B panel resident, A regs loaded

    // ---- barrier-free main loop: 8 chunks x (8 ds_read_b128 + 4 MFMA) ----
    f32x16 acc[4] = {};
    const int rb0 = l31 * DD;           // + ni*32*DD row base within LDS
    #pragma unroll
    for (int t = 0; t < 8; ++t) {
        const int g0 = t * 4 + h0 * 2;          // first granule of this lane's half
        const int p0 = (g0 ^ l31) * 16;
        const int p1 = ((g0 ^ 1) ^ l31) * 16;
        const i32x8 a = __builtin_shufflevector(a4[2 * t], a4[2 * t + 1],
                                                0, 1, 2, 3, 4, 5, 6, 7);
        #pragma unroll
        for (int ni = 0; ni < 4; ++ni) {
            const char* rbase = Bs + rb0 + ni * 32 * DD;
            i32x4 lo = *(const i32x4*)(rbase + p0);
            i32x4 hi = *(const i32x4*)(rbase + p1);
            i32x8 b = __builtin_shufflevector(lo, hi, 0, 1, 2, 3, 4, 5, 6, 7);
            // Unity e8m0 scales (0x7F = 2^0); cbsz/blgp 0 -> fp8 e4m3.
            acc[ni] = __builtin_amdgcn_mfma_scale_f32_32x32x64_f8f6f4(
                a, b, acc[ni], 0, 0, 0, 0x7F7F7F7F, 0, 0x7F7F7F7F);
        }
    }

    // ---- epilogue ----
    // 32x32 C/D layout: col = lane&31, row = (reg&3) + 8*(reg>>2) + 4*(lane>>5)
    // e = exp(10*G - 10) = exp2(G*C - C), C = 10*log2(e).
    const float C10 = 14.42695040888963f;
    float rs[16] = {};
    float cs[4]  = {};
    #pragma unroll
    for (int ni = 0; ni < 4; ++ni) {
        const int gcol = colBase + ni * 32 + l31;
        #pragma unroll
        for (int r = 0; r < 16; ++r) {
            const int lrow = (r & 3) + 8 * (r >> 2) + 4 * h0;
            const int grow = rowBase + wave * 32 + lrow;
            float e = __builtin_amdgcn_exp2f(fmaf(acc[ni][r], C10, -C10));
            if (grow == gcol) e = 0.f;     // exclude diagonal exactly
            rs[r] += e;
            cs[ni] += e;
            // targets: rows 0/1 of G give 10*G[t, j0] transposed.
            // Only bx==0, wave 0, h0==0, r<2 ever hits; disjoint cols -> store.
            if (rowBase == 0 && grow < 2) {
                const int j0 = ((gcol & (BB - 1)) == 0) ? 1 : 0;
                if (grow == j0) targets[gcol] = 10.f * acc[ni][r];
            }
        }
    }
    // row sums: reduce across the 32 col-lanes (both h0 halves hold
    // DIFFERENT rows, so reduce within 32 and write per half).
    #pragma unroll
    for (int m = 1; m <= 16; m <<= 1)
        #pragma unroll
        for (int r = 0; r < 16; ++r)
            rs[r] += __shfl_xor(rs[r], m);
    if (l31 == 0) {
        #pragma unroll
        for (int r = 0; r < 16; ++r)
            atomicAdd(&rowsum[rowBase + wave * 32
                              + (r & 3) + 8 * (r >> 2) + 4 * h0], rs[r]);
    }
    if (!diag) {   // column sums -> transposed-tile row sums
        #pragma unroll
        for (int ni = 0; ni < 4; ++ni)
            cs[ni] += __shfl_xor(cs[ni], 32);   // combine the two k-half row sets
        if (h0 == 0) {
            #pragma unroll
            for (int ni = 0; ni < 4; ++ni)
                atomicAdd(&rowsum[colBase + ni * 32 + l31], cs[ni]);
        }
    }
}

// ---------------- kernel 3: final scalar reduction -------------------------
__global__ __launch_bounds__(1024)
void finalize_kernel(const float* __restrict__ rowsum,
                     const float* __restrict__ targets, float* __restrict__ out) {
    const int tid = threadIdx.x;
    float s = 0.f;
    #pragma unroll
    for (int t = tid; t < NN; t += 1024)
        s += targets[t] - 10.f - __logf(rowsum[t]);
    #pragma unroll
    for (int off = 1; off <= 32; off <<= 1) s += __shfl_xor(s, off);
    __shared__ float red[16];
    if ((tid & 63) == 0) red[tid >> 6] = s;
    __syncthreads();
    if (tid == 0) {
        float t = 0.f;
        #pragma unroll
        for (int i = 0; i < 16; ++i) t += red[i];
        out[0] = -t / (float)NN;
    }
}

extern "C" void kernel_launch(void* const* d_in, const int* in_sizes, int n_in,
                              void* d_out, int out_size, void* d_ws, size_t ws_size,
                              hipStream_t stream) {
    const float* zi = (const float*)d_in[0];
    const float* zj = (const float*)d_in[1];

    unsigned char* M = (unsigned char*)d_ws;                         // 4 MB fp8
    float* rowsum  = (float*)((char*)d_ws + (size_t)NN * DD);        // 32 KB
    float* targets = rowsum + NN;                                    // 32 KB
    float* out = (float*)d_out;

    normalize_kernel<<<NN / 4, 256, 0, stream>>>(zi, zj, M, rowsum);
    gram_lse_kernel<<<NBLK, 256, 0, stream>>>(M, rowsum, targets);
    finalize_kernel<<<1, 1024, 0, stream>>>(rowsum, targets, out);
}

// Round 5
// 107.175 us; speedup vs baseline: 1.0482x; 1.0153x over previous
//
#include <hip/hip_runtime.h>
#include <hip/hip_bf16.h>
#include <hip/hip_fp8.h>

// SimCLR NT-Xent loss on MI355X.
// loss = -(1/2B) sum_t [ 10*G[t,j0(t)] - (10 + log sum_{j!=t} exp(10*G[t,j]-10)) ]
// where G = M M^T, M = l2norm rows of [z_i; z_j], j0 = (t%B==0) ? 1 : 0.
// Round 10: KILL THE ATOMICS. R1-R4 showed duration ~41-52 us invariant to
// compute flavor / barriers / LDS schedule while every pipe sat at 10-25%:
// the shared term was ~1.3M device-scope atomicAdds into the 32KB rowsum
// array (640/block x 2080 blocks, cross-XCD coherence RMWs). Replace with
// disjoint-slice partials: tile (bx,by) plain-stores row-sums to
// rpart[by][panel bx] and col-sums to rpart[bx][panel by] -- exactly one
// writer per (slice,panel) pair, zero collisions, zero RMW. A 32-block
// reduce kernel folds the 64 slices per row. Also: explicit 2-deep A
// prefetch pipeline (R4 VGPR=88 proved the A-register array got sunk into
// the loop as per-chunk global reloads).

#define BB 4096      // batch B
#define DD 512       // feature dim (bytes per row in fp8)
#define NN 8192      // 2B rows of G
#define TILE 128     // block tile (rows x cols)
#define NPAN 64      // NN / TILE panels (= slices)
#define NBLK 2080    // 64*65/2 upper-triangle block tiles

typedef __attribute__((ext_vector_type(4)))  float f32x4;
typedef __attribute__((ext_vector_type(16))) float f32x16;
typedef __attribute__((ext_vector_type(4)))  int   i32x4;
typedef __attribute__((ext_vector_type(8)))  int   i32x8;

#define AS1 __attribute__((address_space(1)))
#define AS3 __attribute__((address_space(3)))
static __device__ __forceinline__ void gload_lds16(const void* g, void* l) {
    __builtin_amdgcn_global_load_lds((const AS1 void*)g, (AS3 void*)l, 16, 0, 0);
}

// ---------------- kernel 1: L2-normalize rows, cast to fp8 -----------------
// One wave per row: 64 lanes x 8 f32, shuffle reduce, no LDS/barrier.
__global__ __launch_bounds__(256)
void normalize_kernel(const float* __restrict__ zi, const float* __restrict__ zj,
                      unsigned char* __restrict__ M, float* __restrict__ wacc) {
    const int wave = threadIdx.x >> 6;
    const int lane = threadIdx.x & 63;
    const int row  = blockIdx.x * 4 + wave;      // 2048 blocks * 4 rows
    if (blockIdx.x == 0 && threadIdx.x == 0) wacc[0] = 0.f;
    const float* src = (row < BB) ? (zi + (size_t)row * DD)
                                  : (zj + (size_t)(row - BB) * DD);
    float4 v0 = ((const float4*)src)[lane * 2 + 0];
    float4 v1 = ((const float4*)src)[lane * 2 + 1];
    float ss = v0.x*v0.x + v0.y*v0.y + v0.z*v0.z + v0.w*v0.w
             + v1.x*v1.x + v1.y*v1.y + v1.z*v1.z + v1.w*v1.w;
    #pragma unroll
    for (int off = 1; off <= 32; off <<= 1) ss += __shfl_xor(ss, off);
    const float inv = rsqrtf(ss);
    const float vals[8] = {v0.x*inv, v0.y*inv, v0.z*inv, v0.w*inv,
                           v1.x*inv, v1.y*inv, v1.z*inv, v1.w*inv};
    union { long u; unsigned char b[8]; } pk;
    #pragma unroll
    for (int j = 0; j < 8; ++j)
        pk.b[j] = __hip_cvt_float_to_fp8(vals[j], __HIP_SATFINITE, __HIP_E4M3);
    ((long*)(M + (size_t)row * DD))[lane] = pk.u;
}

// ---------------- kernel 2: Gram tile + exp partial sums (no atomics) ------
// 2080 blocks, one upper-triangle 128x128 tile each (by >= bx).
// Wave w owns output rows [w*32, w*32+32) x all 128 cols: acc[4] of 32x32.
// A: per-lane registers, 2-deep prefetch pipeline. B: whole panel in LDS,
// granule g of row r stored at pos g^(r&31); staging source carries the
// inverse permutation (gload_lds dest stays lane-linear). Zero bank
// conflicts verified (R4 SQ_LDS_BANK_CONFLICT = 0).
__global__ __launch_bounds__(256, 2)
void gram_lse_kernel(const unsigned char* __restrict__ Mg,
                     float* __restrict__ rpart, float* __restrict__ targets) {
    __shared__ __align__(16) char Bs[TILE * DD];   // 64 KB (cpart overlays tail-use)

    // XCD-banded order: dispatch d -> band d%8 (one XCD), 260 tiles per band.
    const int d = blockIdx.x;
    const int p = (d & 7) * 260 + (d >> 3);
    // triangular decode: p -> (bx, by) with by >= bx
    int by = (int)((sqrtf(8.0f * (float)p + 1.0f) - 1.0f) * 0.5f);
    while ((by + 1) * (by + 2) / 2 <= p) ++by;
    while (by * (by + 1) / 2 > p) --by;
    const int bx = p - by * (by + 1) / 2;

    const int rowBase = bx * TILE;
    const int colBase = by * TILE;
    const bool diag = (bx == by);
    const int tid  = threadIdx.x;
    const int wave = tid >> 6;
    const int lane = tid & 63;
    const int l31 = lane & 31;
    const int h0  = lane >> 5;          // k-half: 0 -> k[0:32), 1 -> k[32:64) per chunk

    // ---- stage whole B panel: 16 issues, 16 B per thread each ----
    // dest granule q = i*256 + tid -> row = q>>5, pos = q&31 = tid&31;
    // stored granule at pos: sg = pos ^ (row&31). Wave dest is lane-linear.
    #pragma unroll
    for (int i = 0; i < 16; ++i) {
        const int row = i * 8 + (tid >> 5);
        const int sg  = (tid & 31) ^ (row & 31);
        gload_lds16(Mg + (size_t)(colBase + row) * DD + sg * 16,
                    Bs + ((size_t)i * 256 + tid) * 16);
    }

    const unsigned char* Arow =
        Mg + (size_t)(rowBase + wave * 32 + l31) * DD + h0 * 32;

    __syncthreads();   // B panel resident

    // ---- barrier-free main loop: 8 chunks x (8 ds_read_b128 + 4 MFMA) ----
    // A prefetch: 2-deep software pipeline (chunk t uses loads issued at t-2).
    f32x16 acc[4] = {};
    const int rb0 = l31 * DD;
    i32x4 c0a = *(const i32x4*)(Arow +   0), c0b = *(const i32x4*)(Arow +  16);
    i32x4 c1a = *(const i32x4*)(Arow +  64), c1b = *(const i32x4*)(Arow +  80);
    #pragma unroll
    for (int t = 0; t < 8; ++t) {
        const i32x8 a = __builtin_shufflevector(c0a, c0b, 0, 1, 2, 3, 4, 5, 6, 7);
        c0a = c1a; c0b = c1b;
        if (t + 2 < 8) {
            c1a = *(const i32x4*)(Arow + (t + 2) * 64);
            c1b = *(const i32x4*)(Arow + (t + 2) * 64 + 16);
        }
        const int g0 = t * 4 + h0 * 2;          // first granule of this lane's half
        const int p0 = (g0 ^ l31) * 16;
        const int p1 = ((g0 ^ 1) ^ l31) * 16;
        #pragma unroll
        for (int ni = 0; ni < 4; ++ni) {
            const char* rbase = Bs + rb0 + ni * 32 * DD;
            i32x4 lo = *(const i32x4*)(rbase + p0);
            i32x4 hi = *(const i32x4*)(rbase + p1);
            i32x8 b = __builtin_shufflevector(lo, hi, 0, 1, 2, 3, 4, 5, 6, 7);
            // Unity e8m0 scales (0x7F = 2^0); cbsz/blgp 0 -> fp8 e4m3.
            acc[ni] = __builtin_amdgcn_mfma_scale_f32_32x32x64_f8f6f4(
                a, b, acc[ni], 0, 0, 0, 0x7F7F7F7F, 0, 0x7F7F7F7F);
        }
    }

    // ---- epilogue ----
    // 32x32 C/D layout: col = lane&31, row = (reg&3) + 8*(reg>>2) + 4*(lane>>5)
    // e = exp(10*G - 10) = exp2(G*C - C), C = 10*log2(e).
    const float C10 = 14.42695040888963f;
    float rs[16] = {};
    float cs[4]  = {};
    #pragma unroll
    for (int ni = 0; ni < 4; ++ni) {
        const int gcol = colBase + ni * 32 + l31;
        #pragma unroll
        for (int r = 0; r < 16; ++r) {
            const int lrow = (r & 3) + 8 * (r >> 2) + 4 * h0;
            const int grow = rowBase + wave * 32 + lrow;
            float e = __builtin_amdgcn_exp2f(fmaf(acc[ni][r], C10, -C10));
            if (grow == gcol) e = 0.f;     // exclude diagonal exactly
            rs[r] += e;
            cs[ni] += e;
            // targets: rows 0/1 of G give 10*G[t, j0] transposed.
            // Only bx==0, wave 0, h0==0, r<2 ever hits; disjoint cols -> store.
            if (rowBase == 0 && grow < 2) {
                const int j0 = ((gcol & (BB - 1)) == 0) ? 1 : 0;
                if (grow == j0) targets[gcol] = 10.f * acc[ni][r];
            }
        }
    }
    // Row sums -> slice `by`, panel bx. Reduce across 32 col-lanes; both h0
    // halves hold different rows. Plain stores: slice (by, panel bx) has
    // exactly one writer (this tile).
    #pragma unroll
    for (int m = 1; m <= 16; m <<= 1)
        #pragma unroll
        for (int r = 0; r < 16; ++r)
            rs[r] += __shfl_xor(rs[r], m);
    if (l31 == 0) {
        #pragma unroll
        for (int r = 0; r < 16; ++r)
            rpart[(size_t)by * NN + rowBase + wave * 32
                  + (r & 3) + 8 * (r >> 2) + 4 * h0] = rs[r];
    }
    // Col sums -> slice `bx`, panel by (skip diag: same sums as rows).
    // Cross-wave reduce via 2KB LDS overlay on Bs (reads done by now).
    if (!diag) {
        #pragma unroll
        for (int ni = 0; ni < 4; ++ni)
            cs[ni] += __shfl_xor(cs[ni], 32);   // combine the two k-half row sets
        float* cpart = (float*)Bs;              // [4][128]
        __syncthreads();                        // all Bs MFMA reads complete
        if (h0 == 0) {
            #pragma unroll
            for (int ni = 0; ni < 4; ++ni)
                cpart[wave * TILE + ni * 32 + l31] = cs[ni];
        }
        __syncthreads();
        if (tid < TILE) {
            float v = cpart[tid] + cpart[TILE + tid]
                    + cpart[2 * TILE + tid] + cpart[3 * TILE + tid];
            rpart[(size_t)bx * NN + colBase + tid] = v;   // coalesced 512B
        }
    }
}

// ---------------- kernel 3: fold 64 slices per row + loss term -------------
// 32 blocks x 256 threads, one row each. Coalesced slice reads (2 MB total).
__global__ __launch_bounds__(256)
void reduce_kernel(const float* __restrict__ rpart,
                   const float* __restrict__ targets, float* __restrict__ wacc) {
    const int i = blockIdx.x * 256 + threadIdx.x;
    float s = 0.f;
    #pragma unroll 8
    for (int sl = 0; sl < NPAN; ++sl)
        s += rpart[(size_t)sl * NN + i];
    float term = targets[i] - 10.f - __logf(s);
    #pragma unroll
    for (int off = 1; off <= 32; off <<= 1) term += __shfl_xor(term, off);
    __shared__ float red[4];
    if ((threadIdx.x & 63) == 0) red[threadIdx.x >> 6] = term;
    __syncthreads();
    if (threadIdx.x == 0)
        atomicAdd(wacc, red[0] + red[1] + red[2] + red[3]);
}

// ---------------- kernel 4: write scalar output ----------------------------
__global__ void write_kernel(const float* __restrict__ wacc,
                             float* __restrict__ out) {
    out[0] = -wacc[0] / (float)NN;
}

extern "C" void kernel_launch(void* const* d_in, const int* in_sizes, int n_in,
                              void* d_out, int out_size, void* d_ws, size_t ws_size,
                              hipStream_t stream) {
    const float* zi = (const float*)d_in[0];
    const float* zj = (const float*)d_in[1];

    unsigned char* M = (unsigned char*)d_ws;                          // 4 MB fp8
    float* rpart   = (float*)((char*)d_ws + (size_t)NN * DD);         // 2 MB
    float* targets = rpart + (size_t)NPAN * NN;                       // 32 KB
    float* wacc    = targets + NN;                                    // 4 B
    float* out = (float*)d_out;

    normalize_kernel<<<NN / 4, 256, 0, stream>>>(zi, zj, M, wacc);
    gram_lse_kernel<<<NBLK, 256, 0, stream>>>(M, rpart, targets);
    reduce_kernel<<<NN / 256, 256, 0, stream>>>(rpart, targets, wacc);
    write_kernel<<<1, 1, 0, stream>>>(wacc, out);
}